// Round 1
// baseline (3368.851 us; speedup 1.0000x reference)
//
#include <hip/hip_runtime.h>

// KMeans predict — robust high-precision scoring (no BLAS rounding emulation).
//   c_sq  = np.sum(c*c, -1)      : numpy pairwise fp32, bit-exact (machine-indep.)
//   dot   = near-exact           : fp32 FMA chains over 32-d chunks, chunk sums
//                                  folded into fp64 (err ~1e-6 ≈ 0.5 ulp of dot)
//   dot32 = (float)dot64         : correctly-rounded fp32 dot
//   score = fl32(-2*dot32 + c_sq): single rounded fp32 add (matches ref tail)
//   out   = argmin, first-index ties (strict '<', ascending k)
// Rationale: the reference's fp32 GEMM rounding is container-dependent; instead
// of imitating it, we compute ~10x more accurately than any fp32 reference can,
// so only tokens whose true top-2 gap < the REFERENCE's own rounding noise
// (~1e-5, expected ≈0.1 tokens in 131072) could mismatch.
// N=131072, D=768, K=1024, fp32 in, int32 out.

#define N_TOK 131072
#define DIMS  768
#define KCL   1024
#define TM    64     // tokens per block
#define TN    128    // clusters per chunk
#define BK    32     // D chunk (fp32 chain length before fp64 fold)
#define XSTRIDE 68   // 64+4: rows 16B-aligned, breaks pow2 bank stride
#define CSTRIDE 132  // 128+4
#define THREADS 256

// ---- numpy pairwise fp32 sum of squares, bit-exact -------------------------
// numpy pairwise_sum: n=768 -> 384+384 -> 192+192 -> 96+96; 96<=128 is the
// 8-accumulator base case; combine ((r0+r1)+(r2+r3))+((r4+r5)+(r6+r7)).
__global__ void csq_np_kernel(const float* __restrict__ c, float* __restrict__ csq) {
    const int k = blockIdx.x * blockDim.x + threadIdx.x;
    if (k >= KCL) return;
    const float* row = c + (size_t)k * DIMS;
    float bsum[8];
    #pragma unroll
    for (int b = 0; b < 8; ++b) {
        const float* a = row + b * 96;
        float r[8];
        #pragma unroll
        for (int j = 0; j < 8; ++j) { const float v = a[j]; r[j] = __fmul_rn(v, v); }
        for (int i = 8; i < 96; i += 8) {
            #pragma unroll
            for (int j = 0; j < 8; ++j) {
                const float v = a[i + j];
                r[j] = __fadd_rn(r[j], __fmul_rn(v, v));
            }
        }
        bsum[b] = __fadd_rn(__fadd_rn(__fadd_rn(r[0], r[1]), __fadd_rn(r[2], r[3])),
                            __fadd_rn(__fadd_rn(r[4], r[5]), __fadd_rn(r[6], r[7])));
    }
    const float s1 = __fadd_rn(__fadd_rn(bsum[0], bsum[1]), __fadd_rn(bsum[2], bsum[3]));
    const float s2 = __fadd_rn(__fadd_rn(bsum[4], bsum[5]), __fadd_rn(bsum[6], bsum[7]));
    csq[k] = __fadd_rn(s1, s2);
}

// ---- main GEMM (chunked fp32 -> fp64 fold) + argmin ------------------------
__launch_bounds__(THREADS, 2)
__global__ void kmeans_hp_kernel(const float* __restrict__ x,
                                 const float* __restrict__ cent,
                                 const float* __restrict__ csq,
                                 int* __restrict__ out) {
    __shared__ __align__(16) float smem[BK * XSTRIDE + BK * CSTRIDE];
    float* Xs = smem;                // [BK][XSTRIDE]  (d-major, token minor)
    float* Cs = smem + BK * XSTRIDE; // [BK][CSTRIDE]

    const int tid = threadIdx.x;
    const int tx  = tid & 15;   // cluster group: 8 clusters
    const int ty  = tid >> 4;   // token group: 4 tokens
    const int m0  = blockIdx.x * TM;
    const int c4  = tid & 7;    // float4 index along D-chunk
    const int r0  = tid >> 3;   // row 0..31

    float b1[4];
    int   i1[4];
    #pragma unroll
    for (int i = 0; i < 4; ++i) { b1[i] = 3.0e38f; i1[i] = 0; }

    for (int nt = 0; nt < KCL; nt += TN) {
        double accd[4][8];      // near-exact dot accumulator
        #pragma unroll
        for (int i = 0; i < 4; ++i)
            #pragma unroll
            for (int j = 0; j < 8; ++j) accd[i][j] = 0.0;

        for (int db = 0; db < DIMS; db += BK) {
            float acc[4][8];    // fp32 chain for this 32-d chunk only
            #pragma unroll
            for (int i = 0; i < 4; ++i)
                #pragma unroll
                for (int j = 0; j < 8; ++j) acc[i][j] = 0.0f;

            // ---- stage X tile: 64 rows x BK, transposed into Xs[d][m] ----
            #pragma unroll
            for (int p = 0; p < 2; ++p) {
                const int r = r0 + p * 32;
                const float4 v = *(const float4*)(x + (size_t)(m0 + r) * DIMS + db + c4 * 4);
                Xs[(c4 * 4 + 0) * XSTRIDE + r] = v.x;
                Xs[(c4 * 4 + 1) * XSTRIDE + r] = v.y;
                Xs[(c4 * 4 + 2) * XSTRIDE + r] = v.z;
                Xs[(c4 * 4 + 3) * XSTRIDE + r] = v.w;
            }
            // ---- stage C tile: 128 rows x BK, transposed into Cs[d][n] ----
            #pragma unroll
            for (int p = 0; p < 4; ++p) {
                const int r = r0 + p * 32;
                const float4 v = *(const float4*)(cent + (size_t)(nt + r) * DIMS + db + c4 * 4);
                Cs[(c4 * 4 + 0) * CSTRIDE + r] = v.x;
                Cs[(c4 * 4 + 1) * CSTRIDE + r] = v.y;
                Cs[(c4 * 4 + 2) * CSTRIDE + r] = v.z;
                Cs[(c4 * 4 + 3) * CSTRIDE + r] = v.w;
            }
            __syncthreads();

            // ---- MAC: fp32 FMA chain over this 32-d chunk ----
            #pragma unroll 8
            for (int d = 0; d < BK; ++d) {
                const float4 a  = *(const float4*)&Xs[d * XSTRIDE + ty * 4];
                const float4 b0 = *(const float4*)&Cs[d * CSTRIDE + tx * 8];
                const float4 bq = *(const float4*)&Cs[d * CSTRIDE + tx * 8 + 4];
                const float av[4] = {a.x, a.y, a.z, a.w};
                const float bv[8] = {b0.x, b0.y, b0.z, b0.w, bq.x, bq.y, bq.z, bq.w};
                #pragma unroll
                for (int i = 0; i < 4; ++i)
                    #pragma unroll
                    for (int j = 0; j < 8; ++j)
                        acc[i][j] = __fmaf_rn(av[i], bv[j], acc[i][j]);
            }
            __syncthreads();

            // ---- fold chunk into fp64 (error-dominating step removed) ----
            #pragma unroll
            for (int i = 0; i < 4; ++i)
                #pragma unroll
                for (int j = 0; j < 8; ++j) accd[i][j] += (double)acc[i][j];
        }

        // ---- epilogue: dot32 = rn(dot64); score = fl(-2*dot32 + c_sq) ----
        #pragma unroll
        for (int j = 0; j < 8; ++j) {
            const int   k  = nt + tx * 8 + j;
            const float cq = csq[k];
            #pragma unroll
            for (int i = 0; i < 4; ++i) {
                const float dot = (float)accd[i][j];                  // correctly rounded
                const float sc  = __fadd_rn(__fmul_rn(-2.0f, dot), cq);
                if (sc < b1[i]) { b1[i] = sc; i1[i] = k; }            // strict <: first index wins
            }
        }
    }

    // ---- cross-thread argmin merge (16 tx groups per token) ----
    __syncthreads();  // tile buffers dead; overlay reduction arrays
    float* rv = smem;                   // [64][17]
    int*   ri = (int*)(smem + TM * 17); // [64][17]
    #pragma unroll
    for (int i = 0; i < 4; ++i) {
        rv[(ty * 4 + i) * 17 + tx] = b1[i];
        ri[(ty * 4 + i) * 17 + tx] = i1[i];
    }
    __syncthreads();
    if (tid < TM) {
        float B = rv[tid * 17];
        int   I = ri[tid * 17];
        #pragma unroll
        for (int t = 1; t < 16; ++t) {
            const float v  = rv[tid * 17 + t];
            const int   ix = ri[tid * 17 + t];
            if (v < B || (v == B && ix < I)) { B = v; I = ix; }
        }
        out[m0 + tid] = I;
    }
}

extern "C" void kernel_launch(void* const* d_in, const int* in_sizes, int n_in,
                              void* d_out, int out_size, void* d_ws, size_t ws_size,
                              hipStream_t stream) {
    const float* x    = (const float*)d_in[0];
    const float* cent = (const float*)d_in[1];
    float* csq = (float*)d_ws;      // 1024 floats scratch
    int*   out = (int*)d_out;

    csq_np_kernel<<<(KCL + 255) / 256, 256, 0, stream>>>(cent, csq);
    kmeans_hp_kernel<<<N_TOK / TM, THREADS, 0, stream>>>(x, cent, csq, out);
}

// Round 2
// 3296.533 us; speedup vs baseline: 1.0219x; 1.0219x over previous
//
#include <hip/hip_runtime.h>

// KMeans predict — robust high-precision scoring, 8x8 register tile.
// NUMERICS ARE BIT-IDENTICAL to the previous passing kernel:
//   c_sq  : numpy pairwise fp32, bit-exact
//   dot   : fp32 FMA chain over 32-d chunks (ascending d), chunk sums folded
//           into fp64 in ascending chunk order; dot32 = (float)dot64
//   score : fl32(-2*dot32 + c_sq); argmin strict '<', first-index ties.
// Perf change only: 8 tok x 8 clu per thread (was 4x8) halves LDS bytes/FMA;
// C tile stored as 16 slots of 12 floats (8 used) + row pad -> all MAC reads
// <=2-way bank conflicts (free); staging writes 4-way on 32 scalars/chunk.
// N=131072, D=768, K=1024, fp32 in, int32 out.

#define N_TOK 131072
#define DIMS  768
#define KCL   1024
#define TM    128    // tokens per block
#define TN    128    // clusters per chunk
#define BK    32     // D chunk (fp32 chain length before fp64 fold)
#define XSTR  132    // X row stride (floats): 128 + 4, 16B-aligned rows
#define CROW  196    // C row stride: 16 slots * 12 + 4 pad, 16B-aligned rows
#define THREADS 256

// ---- numpy pairwise fp32 sum of squares, bit-exact -------------------------
__global__ void csq_np_kernel(const float* __restrict__ c, float* __restrict__ csq) {
    const int k = blockIdx.x * blockDim.x + threadIdx.x;
    if (k >= KCL) return;
    const float* row = c + (size_t)k * DIMS;
    float bsum[8];
    #pragma unroll
    for (int b = 0; b < 8; ++b) {
        const float* a = row + b * 96;
        float r[8];
        #pragma unroll
        for (int j = 0; j < 8; ++j) { const float v = a[j]; r[j] = __fmul_rn(v, v); }
        for (int i = 8; i < 96; i += 8) {
            #pragma unroll
            for (int j = 0; j < 8; ++j) {
                const float v = a[i + j];
                r[j] = __fadd_rn(r[j], __fmul_rn(v, v));
            }
        }
        bsum[b] = __fadd_rn(__fadd_rn(__fadd_rn(r[0], r[1]), __fadd_rn(r[2], r[3])),
                            __fadd_rn(__fadd_rn(r[4], r[5]), __fadd_rn(r[6], r[7])));
    }
    const float s1 = __fadd_rn(__fadd_rn(bsum[0], bsum[1]), __fadd_rn(bsum[2], bsum[3]));
    const float s2 = __fadd_rn(__fadd_rn(bsum[4], bsum[5]), __fadd_rn(bsum[6], bsum[7]));
    csq[k] = __fadd_rn(s1, s2);
}

// ---- main GEMM (chunked fp32 -> fp64 fold) + argmin, 8x8/thread ------------
__launch_bounds__(THREADS, 2)
__global__ void kmeans_hp8_kernel(const float* __restrict__ x,
                                  const float* __restrict__ cent,
                                  const float* __restrict__ csq,
                                  int* __restrict__ out) {
    __shared__ __align__(16) float smem[BK * XSTR + BK * CROW]; // 42 KB
    float* Xs = smem;                // [BK][XSTR]: Xs[d][m], m=token-in-tile
    float* Cs = smem + BK * XSTR;    // [BK][CROW]: slot g (12 floats) = clusters g*8..g*8+7

    const int tid = threadIdx.x;
    const int tx  = tid & 15;   // cluster group: 8 clusters (slot tx)
    const int ty  = tid >> 4;   // token group: 8 tokens
    const int m0  = blockIdx.x * TM;
    const int c4  = tid & 7;    // float4 index along D-chunk
    const int r0  = tid >> 3;   // row 0..31 (4 phases of 32 rows)

    float b1[8];
    int   i1[8];
    #pragma unroll
    for (int i = 0; i < 8; ++i) { b1[i] = 3.0e38f; i1[i] = 0; }

    for (int nt = 0; nt < KCL; nt += TN) {
        double accd[8][8];      // near-exact dot accumulator
        #pragma unroll
        for (int i = 0; i < 8; ++i)
            #pragma unroll
            for (int j = 0; j < 8; ++j) accd[i][j] = 0.0;

        for (int db = 0; db < DIMS; db += BK) {
            float acc[8][8];    // fp32 chain for this 32-d chunk only
            #pragma unroll
            for (int i = 0; i < 8; ++i)
                #pragma unroll
                for (int j = 0; j < 8; ++j) acc[i][j] = 0.0f;

            // ---- stage X tile: 128 rows x BK, transposed into Xs[d][m] ----
            #pragma unroll
            for (int p = 0; p < 4; ++p) {
                const int r = r0 + p * 32;
                const float4 v = *(const float4*)(x + (size_t)(m0 + r) * DIMS + db + c4 * 4);
                Xs[(c4 * 4 + 0) * XSTR + r] = v.x;
                Xs[(c4 * 4 + 1) * XSTR + r] = v.y;
                Xs[(c4 * 4 + 2) * XSTR + r] = v.z;
                Xs[(c4 * 4 + 3) * XSTR + r] = v.w;
            }
            // ---- stage C tile: 128 rows x BK, transposed, slot-12 layout ----
            #pragma unroll
            for (int p = 0; p < 4; ++p) {
                const int r  = r0 + p * 32;
                const int so = (r >> 3) * 12 + (r & 7);
                const float4 v = *(const float4*)(cent + (size_t)(nt + r) * DIMS + db + c4 * 4);
                Cs[(c4 * 4 + 0) * CROW + so] = v.x;
                Cs[(c4 * 4 + 1) * CROW + so] = v.y;
                Cs[(c4 * 4 + 2) * CROW + so] = v.z;
                Cs[(c4 * 4 + 3) * CROW + so] = v.w;
            }
            __syncthreads();

            // ---- MAC: strictly ascending d, one fp32 FMA chain/element ----
            #pragma unroll 2
            for (int d = 0; d < BK; ++d) {
                const float4 a0 = *(const float4*)&Xs[d * XSTR + ty * 8];
                const float4 a1 = *(const float4*)&Xs[d * XSTR + ty * 8 + 4];
                const float4 c0 = *(const float4*)&Cs[d * CROW + tx * 12];
                const float4 c1 = *(const float4*)&Cs[d * CROW + tx * 12 + 4];
                const float av[8] = {a0.x, a0.y, a0.z, a0.w, a1.x, a1.y, a1.z, a1.w};
                const float bv[8] = {c0.x, c0.y, c0.z, c0.w, c1.x, c1.y, c1.z, c1.w};
                #pragma unroll
                for (int i = 0; i < 8; ++i)
                    #pragma unroll
                    for (int j = 0; j < 8; ++j)
                        acc[i][j] = __fmaf_rn(av[i], bv[j], acc[i][j]);
            }
            __syncthreads();

            // ---- fold chunk into fp64 (ascending chunk order preserved) ----
            #pragma unroll
            for (int i = 0; i < 8; ++i)
                #pragma unroll
                for (int j = 0; j < 8; ++j) accd[i][j] += (double)acc[i][j];
        }

        // ---- epilogue: dot32 = rn(dot64); score = fl(-2*dot32 + c_sq) ----
        #pragma unroll
        for (int j = 0; j < 8; ++j) {
            const int   k  = nt + tx * 8 + j;
            const float cq = csq[k];
            #pragma unroll
            for (int i = 0; i < 8; ++i) {
                const float dot = (float)accd[i][j];                  // correctly rounded
                const float sc  = __fadd_rn(__fmul_rn(-2.0f, dot), cq);
                if (sc < b1[i]) { b1[i] = sc; i1[i] = k; }            // strict <: first index wins
            }
        }
    }

    // ---- cross-thread argmin merge (16 tx groups per token) ----
    __syncthreads();  // tile buffers dead; overlay reduction arrays
    float* rv = smem;                   // [128][17]
    int*   ri = (int*)(smem + TM * 17); // [128][17]
    #pragma unroll
    for (int i = 0; i < 8; ++i) {
        rv[(ty * 8 + i) * 17 + tx] = b1[i];
        ri[(ty * 8 + i) * 17 + tx] = i1[i];
    }
    __syncthreads();
    if (tid < TM) {
        float B = rv[tid * 17];
        int   I = ri[tid * 17];
        #pragma unroll
        for (int t = 1; t < 16; ++t) {
            const float v  = rv[tid * 17 + t];
            const int   ix = ri[tid * 17 + t];
            if (v < B || (v == B && ix < I)) { B = v; I = ix; }
        }
        out[m0 + tid] = I;
    }
}

extern "C" void kernel_launch(void* const* d_in, const int* in_sizes, int n_in,
                              void* d_out, int out_size, void* d_ws, size_t ws_size,
                              hipStream_t stream) {
    const float* x    = (const float*)d_in[0];
    const float* cent = (const float*)d_in[1];
    float* csq = (float*)d_ws;      // 1024 floats scratch
    int*   out = (int*)d_out;

    csq_np_kernel<<<(KCL + 255) / 256, 256, 0, stream>>>(cent, csq);
    kmeans_hp8_kernel<<<N_TOK / TM, THREADS, 0, stream>>>(x, cent, csq, out);
}